// Round 16
// baseline (1016.408 us; speedup 1.0000x reference)
//
#include <hip/hip_runtime.h>
#include <hip/hip_bf16.h>
#include <stdint.h>

// Problem constants (from reference)
#define IN_F 4096
#define OUT_F 11008
#define M_ROWS 8192              // 4 * 2048
#define NIG 512                  // IN_FEATURES / IN_GROUP(8)
#define CBSZ 256

typedef _Float16 f16x8 __attribute__((ext_vector_type(8)));
typedef float f32x4 __attribute__((ext_vector_type(4)));

// ---------------------------------------------------------------------------
// Kernel 1: dequantize W (UNSCALED: scales applied in GEMM epilogue in fp32).
// ---------------------------------------------------------------------------
__global__ __launch_bounds__(256) void dequant_w_kernel(
    const int* __restrict__ codes, const float* __restrict__ cbs,
    _Float16* __restrict__ W)
{
  const int idx = blockIdx.x * 256 + threadIdx.x;   // o*512 + g (exact grid)
  const int2 c = ((const int2*)codes)[idx];
  const float4* e0 = (const float4*)(cbs + (size_t)c.x * 8);
  const float4* e1 = (const float4*)(cbs + (size_t)CBSZ * 8 + (size_t)c.y * 8);
  const float4 a0 = e0[0], a1 = e0[1];
  const float4 b0 = e1[0], b1 = e1[1];
  f16x8 w;
  w[0] = (_Float16)(a0.x + b0.x);
  w[1] = (_Float16)(a0.y + b0.y);
  w[2] = (_Float16)(a0.z + b0.z);
  w[3] = (_Float16)(a0.w + b0.w);
  w[4] = (_Float16)(a1.x + b1.x);
  w[5] = (_Float16)(a1.y + b1.y);
  w[6] = (_Float16)(a1.z + b1.z);
  w[7] = (_Float16)(a1.w + b1.w);
  *(f16x8*)(W + (size_t)idx * 8) = w;
}

// ---------------------------------------------------------------------------
// Kernel 2: x fp32 -> f16, 8 elems/thread, vectorized.
// ---------------------------------------------------------------------------
__global__ __launch_bounds__(256) void convert_x_kernel(
    const float* __restrict__ x, _Float16* __restrict__ X)
{
  const size_t i = ((size_t)blockIdx.x * 256 + threadIdx.x) * 8;
  const float4 a = *(const float4*)(x + i);
  const float4 b = *(const float4*)(x + i + 4);
  f16x8 v;
  v[0] = (_Float16)a.x; v[1] = (_Float16)a.y;
  v[2] = (_Float16)a.z; v[3] = (_Float16)a.w;
  v[4] = (_Float16)b.x; v[5] = (_Float16)b.y;
  v[6] = (_Float16)b.z; v[7] = (_Float16)b.w;
  *(f16x8*)(X + i) = v;
}

// ---------------------------------------------------------------------------
// Kernel 3: 128x128x64 f16 GEMM — 2 INDEPENDENT BLOCKS PER CU.
//
// WHY (r6..r15): eight schedule/shape variants at 256² all plateau at
// MfmaUtil 42-46%. Even +6.8e7 bank conflicts (r15) cost zero time -> the
// limiter is neither LDS conflicts nor MFMA count. Common to all variants:
// ONE resident block/CU (128KB LDS), 2 waves/SIMD in barrier lockstep —
// every stall is a dead CU. m97 (874-912 TF, naive drain-per-tile loop!)
// ran ~3 independent blocks/CU; m114: cross-wave overlap is automatic when
// INDEPENDENT waves coexist. This axis was never tested.
//
// Geometry: 128x128 tile, 256 thr = 4 waves (2x2), per-wave 64x64 out
// (4x4 16x16 frags, 64-reg acc). LDS 2 bufs x (A 16KB | B 16KB) = 64KB
// -> 2 blocks/CU (LDS-limited), 8 waves/CU from 2 UNSYNCED blocks.
// Schedule: m97-style simple — stage t+1 at tile start into buf^1 (8
// global_load_lds), two 16-MFMA k-half groups fed by same-phase ds_reads,
// ONE __syncthreads() per tile (publish + WAR; compiler drains vmcnt —
// the drain stall overlaps the OTHER block's compute).
//
// Swizzle (verified 0-conflict r4..r14): chunk_lds = chunk ^ (row&7);
// read offset c = ((q ^ (r16&7)) << 4), q = lane>>4 (16-row frag reads —
// the exact geometry that measured zero). Staging pre-permutes the GLOBAL
// source column (s_col), LDS dest linear.
// ---------------------------------------------------------------------------
#define BM 128
#define BN 128
#define BK 64
#define NKT (IN_F / BK)          // 64
#define GRID_MT (M_ROWS / BM)    // 64
#define GRID_NT (OUT_F / BN)     // 86

__global__ __launch_bounds__(256, 2) void gemm_128(
    const _Float16* __restrict__ X, const _Float16* __restrict__ Wd,
    const float* __restrict__ scales, const float* __restrict__ bias,
    float* __restrict__ out)
{
  __shared__ char smem[65536];   // [2 bufs][A 16KB | B 16KB]

  // T1: XCD swizzle; nwg = 5504, 5504 % 8 == 0 -> simple form bijective
  const int cpx = (GRID_MT * GRID_NT) >> 3;        // 688
  const int wg = (blockIdx.x & 7) * cpx + (blockIdx.x >> 3);
  const int mt = wg & (GRID_MT - 1), nt = wg >> 6; // m-inner: same B-panel per XCD
  const int m0 = mt * BM, n0 = nt * BN;

  const int t_ = threadIdx.x;
  const int wave = t_ >> 6, lane = t_ & 63;
  const int wm = wave >> 1, wn = wave & 1;
  const int r16 = lane & 15;
  const int q = lane >> 4;                         // 16B piece within 64B k-half
  const int sw = r16 & 7;
  const int c0 = ((q ^ sw) << 4);                  // swizzled chunk byte, k-half 0
  const int c1 = (((4 | q) ^ sw) << 4);            // swizzled chunk byte, k-half 1

  // Staging: thread t's 16B lands at linear LDS byte (call*4096 + t*16)
  //   -> row = call*32 + (t>>3), chunk_lds = t&7; logical chunk = (t&7)^((t>>3)&7)
  const int s_row0 = t_ >> 3;                      // 0..31
  const int s_col  = (((t_ & 7) ^ ((t_ >> 3) & 7)) << 3);
  const _Float16* asrc = X  + (size_t)(m0 + s_row0) * IN_F + s_col;
  const _Float16* bsrc = Wd + (size_t)(n0 + s_row0) * IN_F + s_col;
  const int s_dst = wave * 1024;                   // wave-uniform; HW adds lane*16

  f32x4 acc[4][4] = {};                            // 64-reg accumulator
  f16x8 af[4], bf[4];                              // same-phase frags

#define GLD(gsrc, ldst) __builtin_amdgcn_global_load_lds(                     \
    (const __attribute__((address_space(1))) void*)(gsrc),                    \
    (__attribute__((address_space(3))) void*)(ldst), 16, 0, 0)
#define STAGE_A(kt, bufc, i) GLD(asrc + (size_t)(kt) * BK + (size_t)(i) * 32 * IN_F, \
    smem + (bufc) * 32768 + (i) * 4096 + s_dst)
#define STAGE_B(kt, bufc, i) GLD(bsrc + (size_t)(kt) * BK + (size_t)(i) * 32 * IN_F, \
    smem + (bufc) * 32768 + 16384 + (i) * 4096 + s_dst)

#define RD_A(bufp, mf, cc) (*(const f16x8*)((bufp) + ((wm * 64 + (mf) * 16 + r16) << 7) + (cc)))
#define RD_B(bufp, nf, cc) (*(const f16x8*)((bufp) + 16384 + ((wn * 64 + (nf) * 16 + r16) << 7) + (cc)))

#define PRIO1 __builtin_amdgcn_s_setprio(1)
#define PRIO0 __builtin_amdgcn_s_setprio(0)

// 16-MFMA group: full 4x4 frag grid, one k-half
#define MG                                                                    \
    _Pragma("unroll")                                                         \
    for (int mf = 0; mf < 4; ++mf)                                            \
      _Pragma("unroll")                                                       \
      for (int nf = 0; nf < 4; ++nf)                                          \
        acc[mf][nf] = __builtin_amdgcn_mfma_f32_16x16x32_f16(                 \
            af[mf], bf[nf], acc[mf][nf], 0, 0, 0)

// One K-tile. P parity (reads buf[P]; stages t+1 -> buf[1-P]).
#define TILE(P, tt, STG, SYNC) do {                                           \
    const char* bufT = smem + (P) * 32768;                                    \
    if (STG) {                                                                \
      STAGE_A((tt) + 1, 1 - (P), 0); STAGE_A((tt) + 1, 1 - (P), 1);           \
      STAGE_A((tt) + 1, 1 - (P), 2); STAGE_A((tt) + 1, 1 - (P), 3);           \
      STAGE_B((tt) + 1, 1 - (P), 0); STAGE_B((tt) + 1, 1 - (P), 1);           \
      STAGE_B((tt) + 1, 1 - (P), 2); STAGE_B((tt) + 1, 1 - (P), 3);           \
    }                                                                         \
    /* k-half 0: same-phase reads -> MFMA (compiler counted lgkm) */          \
    _Pragma("unroll")                                                         \
    for (int mf = 0; mf < 4; ++mf) af[mf] = RD_A(bufT, mf, c0);               \
    _Pragma("unroll")                                                         \
    for (int nf = 0; nf < 4; ++nf) bf[nf] = RD_B(bufT, nf, c0);               \
    PRIO1; MG; PRIO0;                                                         \
    /* k-half 1 */                                                            \
    _Pragma("unroll")                                                         \
    for (int mf = 0; mf < 4; ++mf) af[mf] = RD_A(bufT, mf, c1);               \
    _Pragma("unroll")                                                         \
    for (int nf = 0; nf < 4; ++nf) bf[nf] = RD_B(bufT, nf, c1);               \
    PRIO1; MG; PRIO0;                                                         \
    if (SYNC) __syncthreads();  /* publish t+1; WAR-release buf[1-P];         \
                                   drain overlaps the OTHER resident block */ \
  } while (0)

  // ---- Prologue: stage tile 0 into buf0, publish
  STAGE_A(0, 0, 0); STAGE_A(0, 0, 1); STAGE_A(0, 0, 2); STAGE_A(0, 0, 3);
  STAGE_B(0, 0, 0); STAGE_B(0, 0, 1); STAGE_B(0, 0, 2); STAGE_B(0, 0, 3);
  __syncthreads();

  // ---- Main loop: tiles 0..62 stage next; tile 63 bare
  #pragma unroll 1
  for (int t = 0; t < 62; t += 2) {
    TILE(0, t,     1, 1);
    TILE(1, t + 1, 1, 1);
  }
  TILE(0, 62, 1, 1);
  TILE(1, 63, 0, 0);

  // Epilogue: acc * scales[col] + bias[col], fp32.
  // C/D frag: col = lane&15, row = (lane>>4)*4 + reg (m89-verified).
  const int crow = (lane >> 4) << 2;
  #pragma unroll
  for (int nf = 0; nf < 4; ++nf) {
    const int col = n0 + wn * 64 + nf * 16 + r16;
    const float s = scales[col];
    const float bb = bias[col];
    #pragma unroll
    for (int mf = 0; mf < 4; ++mf) {
      const int rb = m0 + wm * 64 + mf * 16 + crow;
      #pragma unroll
      for (int r = 0; r < 4; ++r)
        out[(size_t)(rb + r) * OUT_F + col] = acc[mf][nf][r] * s + bb;
    }
  }
#undef TILE
#undef MG
#undef RD_A
#undef RD_B
#undef STAGE_A
#undef STAGE_B
#undef GLD
}

// ---------------------------------------------------------------------------
// Fallback (only if ws too small): correct but slow fp32 path.
// ---------------------------------------------------------------------------
__global__ __launch_bounds__(256) void naive_kernel(
    const float* __restrict__ x, const int* __restrict__ codes,
    const float* __restrict__ cbs, const float* __restrict__ scales,
    const float* __restrict__ bias, float* __restrict__ out)
{
  __shared__ float xrow[IN_F];
  const int m = blockIdx.x;
  for (int i = threadIdx.x; i < IN_F; i += 256)
    xrow[i] = x[(size_t)m * IN_F + i];
  __syncthreads();
  for (int o = threadIdx.x; o < OUT_F; o += 256) {
    float acc = 0.f;
    const int2* crow = (const int2*)codes + (size_t)o * NIG;
    for (int g = 0; g < NIG; ++g) {
      const int2 c = crow[g];
      const float* e0 = cbs + (size_t)c.x * 8;
      const float* e1 = cbs + (size_t)CBSZ * 8 + (size_t)c.y * 8;
      const float* xr = xrow + g * 8;
      #pragma unroll
      for (int j = 0; j < 8; ++j) acc += (e0[j] + e1[j]) * xr[j];
    }
    out[(size_t)m * OUT_F + o] = acc * scales[o] + bias[o];
  }
}

// ---------------------------------------------------------------------------
extern "C" void kernel_launch(void* const* d_in, const int* in_sizes, int n_in,
                              void* d_out, int out_size, void* d_ws, size_t ws_size,
                              hipStream_t stream) {
  const float* x      = (const float*)d_in[0];
  const int*   codes  = (const int*)d_in[1];
  const float* cbs    = (const float*)d_in[2];
  const float* scales = (const float*)d_in[3];
  const float* bias   = (const float*)d_in[4];
  float* out = (float*)d_out;

  const size_t W_BYTES = (size_t)OUT_F * IN_F * sizeof(_Float16);  // 90.2 MB
  const size_t X_BYTES = (size_t)M_ROWS * IN_F * sizeof(_Float16); // 67.1 MB

  if (ws_size < W_BYTES + X_BYTES) {
    naive_kernel<<<M_ROWS, 256, 0, stream>>>(x, codes, cbs, scales, bias, out);
    return;
  }

  _Float16* W = (_Float16*)d_ws;
  _Float16* X = (_Float16*)((char*)d_ws + W_BYTES);

  dequant_w_kernel<<<(OUT_F * NIG) / 256, 256, 0, stream>>>(codes, cbs, W);
  convert_x_kernel<<<(M_ROWS * IN_F / 8) / 256, 256, 0, stream>>>(x, X);
  gemm_128<<<GRID_MT * GRID_NT, 256, 0, stream>>>(X, W, scales, bias, out);
}

// Round 17
// 788.529 us; speedup vs baseline: 1.2890x; 1.2890x over previous
//
#include <hip/hip_runtime.h>
#include <hip/hip_bf16.h>
#include <stdint.h>

// Problem constants (from reference)
#define IN_F 4096
#define OUT_F 11008
#define M_ROWS 8192              // 4 * 2048
#define NIG 512                  // IN_FEATURES / IN_GROUP(8)
#define CBSZ 256

typedef _Float16 f16x8 __attribute__((ext_vector_type(8)));
typedef float f32x4 __attribute__((ext_vector_type(4)));

// ---------------------------------------------------------------------------
// Kernel 1: fused prep — blocks [0, 22016) dequantize W (unscaled; scales
// applied in GEMM epilogue), blocks [22016, 38400) convert x fp32->f16.
// Merged to save one launch gap (both memory-bound, disjoint outputs).
// ---------------------------------------------------------------------------
#define DQ_BLOCKS ((OUT_F * NIG) / 256)            // 22016
#define CV_BLOCKS ((M_ROWS * IN_F / 8) / 256)      // 16384

__global__ __launch_bounds__(256) void prep_kernel(
    const int* __restrict__ codes, const float* __restrict__ cbs,
    const float* __restrict__ x,
    _Float16* __restrict__ W, _Float16* __restrict__ X)
{
  if (blockIdx.x < DQ_BLOCKS) {
    const int idx = blockIdx.x * 256 + threadIdx.x;   // o*512 + g (exact)
    const int2 c = ((const int2*)codes)[idx];
    const float4* e0 = (const float4*)(cbs + (size_t)c.x * 8);
    const float4* e1 = (const float4*)(cbs + (size_t)CBSZ * 8 + (size_t)c.y * 8);
    const float4 a0 = e0[0], a1 = e0[1];
    const float4 b0 = e1[0], b1 = e1[1];
    f16x8 w;
    w[0] = (_Float16)(a0.x + b0.x);
    w[1] = (_Float16)(a0.y + b0.y);
    w[2] = (_Float16)(a0.z + b0.z);
    w[3] = (_Float16)(a0.w + b0.w);
    w[4] = (_Float16)(a1.x + b1.x);
    w[5] = (_Float16)(a1.y + b1.y);
    w[6] = (_Float16)(a1.z + b1.z);
    w[7] = (_Float16)(a1.w + b1.w);
    *(f16x8*)(W + (size_t)idx * 8) = w;
  } else {
    const size_t i = ((size_t)(blockIdx.x - DQ_BLOCKS) * 256 + threadIdx.x) * 8;
    const float4 a = *(const float4*)(x + i);
    const float4 b = *(const float4*)(x + i + 4);
    f16x8 v;
    v[0] = (_Float16)a.x; v[1] = (_Float16)a.y;
    v[2] = (_Float16)a.z; v[3] = (_Float16)a.w;
    v[4] = (_Float16)b.x; v[5] = (_Float16)b.y;
    v[6] = (_Float16)b.z; v[7] = (_Float16)b.w;
    *(f16x8*)(X + i) = v;
  }
}

// ---------------------------------------------------------------------------
// Kernel 2: 256x256x64 f16 GEMM — r14 verbatim (best measured: GEMM 743-779us,
// MfmaUtil 45-46, VGPR 128, 0 conflicts): r6's modulo 8-phase pipeline +
// T19 sched_group_barrier per-phase interleave.
//
// CONVERGENCE NOTE (r6..r16): nine variants across schedule (r6/r9/r10/r11/
// r12/r14), MFMA shape (r15: 32x32x16), memory path (r13: B-direct-to-reg),
// and occupancy (r16: 128² x 2 blocks/CU) ALL land at MfmaUtil 42-46% or
// worse. r14 is the best; the residual vs m201's 62% is not movable by
// plain-HIP source changes for this problem (grid tail ~11% is baked in by
// GRID_NT=43 prime; the rest is addressing micro-opt / hand-asm territory).
//
// r6 schedule per tile t (8 phases, 1 BAR each; MFMA consumes prev-phase
// reads; compiler emits counted lgkm automatically):
//   q1: Q1k0=al0*bl0[P] | rd al1(4)  | stg A_h0(t+1)->bufN
//   q2: Q1k1=al1*bl1    | rd bh1(2)  | stg A_h1(t+1)->bufN
//   q3: Q2k1=al1*bh1    | rd bh0(2)  |
//   q4: Q2k0=al0*bh0    | rd ah0(4)  |
//   q5: Q3k0=ah0*bh0    | rd ah1(4)  |
//   q6: Q3k1=ah1*bh1    |            | gate vmcnt(4)
//   q7: Q4k1=ah1*bl1    | rd bl0'(2) | stg B_h0(t+2)->bufT, vmcnt(2)
//   q8: Q4k0=ah0*bl0[P] | rd al0',bl1'(6) | stg B_h1(t+2)->bufT
// Gates: VM4 at q6 proves B(t+1) landed before q7 bl0' read; VM2 at q7
// proves A(t+1) landed before q8 al0' read. In-flight 4-8, drains at t=62.
// blo double-generation (q1 use vs q7 read wraps tile boundary).
// Swizzle (0 conflicts measured r4/r6/r9/r10/r14): chunk_lds = chunk ^
// (row&7); read applies XOR, staging pre-permutes GLOBAL source column.
// ---------------------------------------------------------------------------
#define BM 256
#define BN 256
#define BK 64
#define NKT (IN_F / BK)          // 64
#define GRID_MT (M_ROWS / BM)    // 32
#define GRID_NT (OUT_F / BN)     // 43

__global__ __launch_bounds__(512, 2) void gemm_pipe(
    const _Float16* __restrict__ X, const _Float16* __restrict__ Wd,
    const float* __restrict__ scales, const float* __restrict__ bias,
    float* __restrict__ out)
{
  __shared__ char smem[131072];  // [2 bufs][A 32KB | B 32KB]

  // T1: XCD swizzle; nwg = 1376 % 8 == 0 -> simple form bijective
  const int cpx = (GRID_MT * GRID_NT) >> 3;        // 172
  const int wg = (blockIdx.x & 7) * cpx + (blockIdx.x >> 3);
  const int mt = wg & (GRID_MT - 1), nt = wg >> 5; // m-inner: same B-panel per XCD
  const int m0 = mt * BM, n0 = nt * BN;

  const int t_ = threadIdx.x;
  const int wave = t_ >> 6, lane = t_ & 63;
  const int wm = wave >> 2, wn = wave & 3;
  const int r16 = lane & 15;
  const int q = lane >> 4;                         // 16B piece within 64B k-half
  const int sw = r16 & 7;                          // row&7 (rows offset by mult of 16)
  const int c0 = ((q ^ sw) << 4);                  // swizzled chunk byte, k-half 0
  const int c1 = (((4 | q) ^ sw) << 4);            // swizzled chunk byte, k-half 1

  // Staging: thread t's 16B lands at linear LDS byte (call*8192 + t*16)
  //   -> row = call*64 + (t>>3), chunk_lds = t&7; logical chunk = (t&7)^((t>>3)&7)
  const int s_row0 = t_ >> 3;
  const int s_col  = (((t_ & 7) ^ ((t_ >> 3) & 7)) << 3);
  const _Float16* asrc = X  + (size_t)(m0 + s_row0) * IN_F + s_col;
  const _Float16* bsrc = Wd + (size_t)(n0 + s_row0) * IN_F + s_col;
  const int s_dst = wave * 1024;                   // wave-uniform; HW adds lane*16

  f32x4 acc[8][4] = {};
  // Fragment register classes (per modulo schedule). blo_k0 double-gen.
  f16x8 al0[4], al1[4], ah0[4], ah1[4];
  f16x8 bl0[2][2], bl1[2], bh0[2], bh1[2];

#define GLD(gsrc, ldst) __builtin_amdgcn_global_load_lds(                     \
    (const __attribute__((address_space(1))) void*)(gsrc),                    \
    (__attribute__((address_space(3))) void*)(ldst), 16, 0, 0)
#define STAGE_A(kt, bufc, i) GLD(asrc + (size_t)(kt) * BK + (size_t)(i) * 64 * IN_F, \
    smem + (bufc) * 65536 + (i) * 8192 + s_dst)
#define STAGE_B(kt, bufc, i) GLD(bsrc + (size_t)(kt) * BK + (size_t)(i) * 64 * IN_F, \
    smem + (bufc) * 65536 + 32768 + (i) * 8192 + s_dst)

#define RD_A(bufp, mm, cc) (*(const f16x8*)((bufp) + ((wm * 128 + (mm) * 16 + r16) << 7) + (cc)))
#define RD_B(bufp, nn, cc) (*(const f16x8*)((bufp) + 32768 + ((wn * 64 + (nn) * 16 + r16) << 7) + (cc)))

#define BAR   __builtin_amdgcn_s_barrier()
#define PRIO1 __builtin_amdgcn_s_setprio(1)
#define PRIO0 __builtin_amdgcn_s_setprio(0)
#define VM4 asm volatile("s_waitcnt vmcnt(4)" ::: "memory")
#define VM2 asm volatile("s_waitcnt vmcnt(2)" ::: "memory")
#define VM0 asm volatile("s_waitcnt vmcnt(0)" ::: "memory")

// T19 sched_group_barrier helpers (masks: MFMA=0x8, DS_READ=0x100,
// VMEM|VMEM_READ=0x30 for global_load_lds)
#define SGM(n) __builtin_amdgcn_sched_group_barrier(0x8, n, 0)
#define SGD(n) __builtin_amdgcn_sched_group_barrier(0x100, n, 0)
#define SGV(n) __builtin_amdgcn_sched_group_barrier(0x30, n, 0)
#define MD1 SGM(1); SGD(1)

// 8-MFMA group: 4 m-frags x 2 n-frags into acc[MO..][NO..]
#define MG(AF, BF, MO, NO)                                                    \
    _Pragma("unroll")                                                         \
    for (int m = 0; m < 4; ++m)                                               \
      _Pragma("unroll")                                                       \
      for (int n = 0; n < 2; ++n)                                             \
        acc[(MO) + m][(NO) + n] = __builtin_amdgcn_mfma_f32_16x16x32_f16(     \
            AF[m], BF[n], acc[(MO) + m][(NO) + n], 0, 0, 0)

// One K-tile. P: parity literal. SA: stage A(t+1). SB: stage B(t+2).
// GB: q6 gate vmcnt(4). GA: q7 gate mode (2 -> vmcnt(2), 0 -> vmcnt(0), -1 none).
#define TILE(P, tt, SA, SB, GB, GA) do {                                      \
    char* bufT = smem + (P) * 65536;                                          \
    char* bufN = smem + (1 - (P)) * 65536;                                    \
    /* q1: 8 MFMA, 4 reads, [2 stages] */                                     \
    if (SA) { STAGE_A((tt) + 1, 1 - (P), 0); STAGE_A((tt) + 1, 1 - (P), 1); } \
    _Pragma("unroll")                                                         \
    for (int m = 0; m < 4; ++m) al1[m] = RD_A(bufT, m, c1);                   \
    PRIO1; MG(al0, bl0[P], 0, 0); PRIO0;                                      \
    SGM(1); if (SA) { SGV(2); }                                               \
    MD1; MD1; MD1; MD1; SGM(3);                                               \
    BAR;                                                                      \
    /* q2: 8 MFMA, 2 reads, [2 stages] */                                     \
    if (SA) { STAGE_A((tt) + 1, 1 - (P), 2); STAGE_A((tt) + 1, 1 - (P), 3); } \
    _Pragma("unroll")                                                         \
    for (int n = 0; n < 2; ++n) bh1[n] = RD_B(bufT, 2 + n, c1);               \
    PRIO1; MG(al1, bl1, 0, 0); PRIO0;                                         \
    SGM(1); if (SA) { SGV(2); }                                               \
    MD1; MD1; SGM(5);                                                         \
    BAR;                                                                      \
    /* q3: 8 MFMA, 2 reads */                                                 \
    _Pragma("unroll")                                                         \
    for (int n = 0; n < 2; ++n) bh0[n] = RD_B(bufT, 2 + n, c0);               \
    PRIO1; MG(al1, bh1, 0, 2); PRIO0;                                         \
    MD1; MD1; SGM(6);                                                         \
    BAR;                                                                      \
    /* q4: 8 MFMA, 4 reads */                                                 \
    _Pragma("unroll")                                                         \
    for (int m = 0; m < 4; ++m) ah0[m] = RD_A(bufT, 4 + m, c0);               \
    PRIO1; MG(al0, bh0, 0, 2); PRIO0;                                         \
    MD1; MD1; MD1; MD1; SGM(4);                                               \
    BAR;                                                                      \
    /* q5: 8 MFMA, 4 reads */                                                 \
    _Pragma("unroll")                                                         \
    for (int m = 0; m < 4; ++m) ah1[m] = RD_A(bufT, 4 + m, c1);               \
    PRIO1; MG(ah0, bh0, 4, 2); PRIO0;                                         \
    MD1; MD1; MD1; MD1; SGM(4);                                               \
    BAR;                                                                      \
    /* q6: 8 MFMA; gate vmcnt(4) */                                           \
    PRIO1; MG(ah1, bh1, 4, 2); PRIO0;                                         \
    SGM(8);                                                                   \
    if (GB) { VM4; }                                                          \
    BAR;                                                                      \
    /* q7: 8 MFMA, 2 reads, [2 stages]; gate */                               \
    if (SB) { STAGE_B((tt) + 2, P, 0); STAGE_B((tt) + 2, P, 1); }             \
    _Pragma("unroll")                                                         \
    for (int n = 0; n < 2; ++n) bl0[1 - (P)][n] = RD_B(bufN, n, c0);          \
    PRIO1; MG(ah1, bl1, 4, 0); PRIO0;                                         \
    SGM(1); if (SB) { SGV(2); }                                               \
    MD1; MD1; SGM(5);                                                         \
    if ((GA) == 2) { VM2; }                                                   \
    if ((GA) == 0) { VM0; }                                                   \
    BAR;                                                                      \
    /* q8: 8 MFMA, 6 reads, [2 stages] */                                     \
    if (SB) { STAGE_B((tt) + 2, P, 2); STAGE_B((tt) + 2, P, 3); }             \
    _Pragma("unroll")                                                         \
    for (int m = 0; m < 4; ++m) al0[m] = RD_A(bufN, m, c0);                   \
    _Pragma("unroll")                                                         \
    for (int n = 0; n < 2; ++n) bl1[n] = RD_B(bufN, n, c1);                   \
    PRIO1; MG(ah0, bl0[P], 4, 0); PRIO0;                                      \
    SGM(1); if (SB) { SGV(2); }                                               \
    MD1; MD1; MD1; MD1; MD1; MD1; SGM(1);                                     \
    BAR;                                                                      \
  } while (0)

  // ---- Prologue: tile0 full (8 calls) + tile1 B (4 calls); enter steady state
  {
    _Pragma("unroll")
    for (int i = 0; i < 4; ++i) { STAGE_A(0, 0, i); }
    _Pragma("unroll")
    for (int i = 0; i < 4; ++i) { STAGE_B(0, 0, i); }
    _Pragma("unroll")
    for (int i = 0; i < 4; ++i) { STAGE_B(1, 1, i); }
    VM4;                                   // tile0's 8 landed; tile1-B 4 in flight
    BAR;
    // Preload registers the steady loop expects (normally read at q7/q8(t-1)):
    char* buf0p = smem;
    _Pragma("unroll")
    for (int n = 0; n < 2; ++n) bl0[0][n] = RD_B(buf0p, n, c0);
    _Pragma("unroll")
    for (int n = 0; n < 2; ++n) bl1[n] = RD_B(buf0p, n, c1);
    _Pragma("unroll")
    for (int m = 0; m < 4; ++m) al0[m] = RD_A(buf0p, m, c0);
  }

  // ---- Main loop: tiles 0..61 (full pipeline)
  #pragma unroll 1
  for (int t = 0; t < 62; t += 2) {
    TILE(0, t,     1, 1, 1, 2);
    TILE(1, t + 1, 1, 1, 1, 2);
  }
  // ---- Tail: tile 62 (stage A(63) only; drain gate), tile 63 (no stages/gates;
  // its q7/q8 prefetch-reads fetch stale LDS, dead values — harmless)
  TILE(0, 62, 1, 0, 1, 0);
  TILE(1, 63, 0, 0, 0, -1);

  // Epilogue: acc * scales[col] + bias[col], fp32.
  // C/D frag: col = lane&15, row = (lane>>4)*4 + reg (m89-verified).
  const int crow = (lane >> 4) << 2;
  #pragma unroll
  for (int nf = 0; nf < 4; ++nf) {
    const int col = n0 + wn * 64 + nf * 16 + r16;
    const float s = scales[col];
    const float bb = bias[col];
    #pragma unroll
    for (int mf = 0; mf < 8; ++mf) {
      const int rb = m0 + wm * 128 + mf * 16 + crow;
      #pragma unroll
      for (int r = 0; r < 4; ++r)
        out[(size_t)(rb + r) * OUT_F + col] = acc[mf][nf][r] * s + bb;
    }
  }
#undef TILE
#undef MG
#undef RD_A
#undef RD_B
#undef STAGE_A
#undef STAGE_B
#undef GLD
}

// ---------------------------------------------------------------------------
// Fallback (only if ws too small): correct but slow fp32 path.
// ---------------------------------------------------------------------------
__global__ __launch_bounds__(256) void naive_kernel(
    const float* __restrict__ x, const int* __restrict__ codes,
    const float* __restrict__ cbs, const float* __restrict__ scales,
    const float* __restrict__ bias, float* __restrict__ out)
{
  __shared__ float xrow[IN_F];
  const int m = blockIdx.x;
  for (int i = threadIdx.x; i < IN_F; i += 256)
    xrow[i] = x[(size_t)m * IN_F + i];
  __syncthreads();
  for (int o = threadIdx.x; o < OUT_F; o += 256) {
    float acc = 0.f;
    const int2* crow = (const int2*)codes + (size_t)o * NIG;
    for (int g = 0; g < NIG; ++g) {
      const int2 c = crow[g];
      const float* e0 = cbs + (size_t)c.x * 8;
      const float* e1 = cbs + (size_t)CBSZ * 8 + (size_t)c.y * 8;
      const float* xr = xrow + g * 8;
      #pragma unroll
      for (int j = 0; j < 8; ++j) acc += (e0[j] + e1[j]) * xr[j];
    }
    out[(size_t)m * OUT_F + o] = acc * scales[o] + bias[o];
  }
}

// ---------------------------------------------------------------------------
extern "C" void kernel_launch(void* const* d_in, const int* in_sizes, int n_in,
                              void* d_out, int out_size, void* d_ws, size_t ws_size,
                              hipStream_t stream) {
  const float* x      = (const float*)d_in[0];
  const int*   codes  = (const int*)d_in[1];
  const float* cbs    = (const float*)d_in[2];
  const float* scales = (const float*)d_in[3];
  const float* bias   = (const float*)d_in[4];
  float* out = (float*)d_out;

  const size_t W_BYTES = (size_t)OUT_F * IN_F * sizeof(_Float16);  // 90.2 MB
  const size_t X_BYTES = (size_t)M_ROWS * IN_F * sizeof(_Float16); // 67.1 MB

  if (ws_size < W_BYTES + X_BYTES) {
    naive_kernel<<<M_ROWS, 256, 0, stream>>>(x, codes, cbs, scales, bias, out);
    return;
  }

  _Float16* W = (_Float16*)d_ws;
  _Float16* X = (_Float16*)((char*)d_ws + W_BYTES);

  prep_kernel<<<DQ_BLOCKS + CV_BLOCKS, 256, 0, stream>>>(codes, cbs, x, W, X);
  gemm_pipe<<<GRID_MT * GRID_NT, 512, 0, stream>>>(X, W, scales, bias, out);
}

// Round 18
// 770.520 us; speedup vs baseline: 1.3191x; 1.0234x over previous
//
#include <hip/hip_runtime.h>
#include <hip/hip_bf16.h>
#include <stdint.h>

// Problem constants (from reference)
#define IN_F 4096
#define OUT_F 11008
#define M_ROWS 8192              // 4 * 2048
#define NIG 512                  // IN_FEATURES / IN_GROUP(8)
#define CBSZ 256

typedef _Float16 f16x8 __attribute__((ext_vector_type(8)));
typedef float f32x4 __attribute__((ext_vector_type(4)));

// ---------------------------------------------------------------------------
// Kernel 1: fused prep — blocks [0, 22016) dequantize W (unscaled; scales
// applied in GEMM epilogue), blocks [22016, 38400) convert x fp32->f16.
// Stores stay CACHEABLE (X/W are read back immediately by the GEMM).
// ---------------------------------------------------------------------------
#define DQ_BLOCKS ((OUT_F * NIG) / 256)            // 22016
#define CV_BLOCKS ((M_ROWS * IN_F / 8) / 256)      // 16384

__global__ __launch_bounds__(256) void prep_kernel(
    const int* __restrict__ codes, const float* __restrict__ cbs,
    const float* __restrict__ x,
    _Float16* __restrict__ W, _Float16* __restrict__ X)
{
  if (blockIdx.x < DQ_BLOCKS) {
    const int idx = blockIdx.x * 256 + threadIdx.x;   // o*512 + g (exact)
    const int2 c = ((const int2*)codes)[idx];
    const float4* e0 = (const float4*)(cbs + (size_t)c.x * 8);
    const float4* e1 = (const float4*)(cbs + (size_t)CBSZ * 8 + (size_t)c.y * 8);
    const float4 a0 = e0[0], a1 = e0[1];
    const float4 b0 = e1[0], b1 = e1[1];
    f16x8 w;
    w[0] = (_Float16)(a0.x + b0.x);
    w[1] = (_Float16)(a0.y + b0.y);
    w[2] = (_Float16)(a0.z + b0.z);
    w[3] = (_Float16)(a0.w + b0.w);
    w[4] = (_Float16)(a1.x + b1.x);
    w[5] = (_Float16)(a1.y + b1.y);
    w[6] = (_Float16)(a1.z + b1.z);
    w[7] = (_Float16)(a1.w + b1.w);
    *(f16x8*)(W + (size_t)idx * 8) = w;
  } else {
    const size_t i = ((size_t)(blockIdx.x - DQ_BLOCKS) * 256 + threadIdx.x) * 8;
    const float4 a = *(const float4*)(x + i);
    const float4 b = *(const float4*)(x + i + 4);
    f16x8 v;
    v[0] = (_Float16)a.x; v[1] = (_Float16)a.y;
    v[2] = (_Float16)a.z; v[3] = (_Float16)a.w;
    v[4] = (_Float16)b.x; v[5] = (_Float16)b.y;
    v[6] = (_Float16)b.z; v[7] = (_Float16)b.w;
    *(f16x8*)(X + i) = v;
  }
}

// ---------------------------------------------------------------------------
// Kernel 2: 256x256x64 f16 GEMM — r14/r17 structure (best measured: GEMM
// 743-779us, MfmaUtil 45-48, 0 conflicts) + NONTEMPORAL OUT STORES.
//
// NT-STORE RATIONALE (r18 lever): FETCH_SIZE = 1.5GB/dispatch vs 157MB of
// inputs (9.5x over-fetch) although X+W (157MB) < L3 (256MB). Mechanism:
// the epilogue streams 335MB of OUT through L3 every dispatch, cycling the
// whole L3 and evicting X/W -> staging runs at ~27% HBM-miss mix. OUT is
// written once, never re-read -> __builtin_nontemporal_store bypasses L3,
// X+W stay resident, staging becomes L3-fed. All nine r6-r16 variants
// shared this staging feed — consistent with the common 42-48% plateau.
//
// r6 schedule per tile t (8 phases, 1 BAR each; MFMA consumes prev-phase
// reads; compiler emits counted lgkm automatically):
//   q1: Q1k0=al0*bl0[P] | rd al1(4)  | stg A_h0(t+1)->bufN
//   q2: Q1k1=al1*bl1    | rd bh1(2)  | stg A_h1(t+1)->bufN
//   q3: Q2k1=al1*bh1    | rd bh0(2)  |
//   q4: Q2k0=al0*bh0    | rd ah0(4)  |
//   q5: Q3k0=ah0*bh0    | rd ah1(4)  |
//   q6: Q3k1=ah1*bh1    |            | gate vmcnt(4)
//   q7: Q4k1=ah1*bl1    | rd bl0'(2) | stg B_h0(t+2)->bufT, vmcnt(2)
//   q8: Q4k0=ah0*bl0[P] | rd al0',bl1'(6) | stg B_h1(t+2)->bufT
// Gates: VM4 at q6 proves B(t+1) landed before q7 bl0' read; VM2 at q7
// proves A(t+1) landed before q8 al0' read. In-flight 4-8, drains at t=62.
// blo double-generation (q1 use vs q7 read wraps tile boundary).
// Swizzle (0 conflicts measured r4..r17): chunk_lds = chunk ^ (row&7);
// read applies XOR, staging pre-permutes GLOBAL source column.
// T19 SGB chains pin per-phase MFMA/ds_read/stage interleave (r14).
// ---------------------------------------------------------------------------
#define BM 256
#define BN 256
#define BK 64
#define NKT (IN_F / BK)          // 64
#define GRID_MT (M_ROWS / BM)    // 32
#define GRID_NT (OUT_F / BN)     // 43

__global__ __launch_bounds__(512, 2) void gemm_pipe(
    const _Float16* __restrict__ X, const _Float16* __restrict__ Wd,
    const float* __restrict__ scales, const float* __restrict__ bias,
    float* __restrict__ out)
{
  __shared__ char smem[131072];  // [2 bufs][A 32KB | B 32KB]

  // T1: XCD swizzle; nwg = 1376 % 8 == 0 -> simple form bijective
  const int cpx = (GRID_MT * GRID_NT) >> 3;        // 172
  const int wg = (blockIdx.x & 7) * cpx + (blockIdx.x >> 3);
  const int mt = wg & (GRID_MT - 1), nt = wg >> 5; // m-inner: same B-panel per XCD
  const int m0 = mt * BM, n0 = nt * BN;

  const int t_ = threadIdx.x;
  const int wave = t_ >> 6, lane = t_ & 63;
  const int wm = wave >> 2, wn = wave & 3;
  const int r16 = lane & 15;
  const int q = lane >> 4;                         // 16B piece within 64B k-half
  const int sw = r16 & 7;                          // row&7 (rows offset by mult of 16)
  const int c0 = ((q ^ sw) << 4);                  // swizzled chunk byte, k-half 0
  const int c1 = (((4 | q) ^ sw) << 4);            // swizzled chunk byte, k-half 1

  // Staging: thread t's 16B lands at linear LDS byte (call*8192 + t*16)
  //   -> row = call*64 + (t>>3), chunk_lds = t&7; logical chunk = (t&7)^((t>>3)&7)
  const int s_row0 = t_ >> 3;
  const int s_col  = (((t_ & 7) ^ ((t_ >> 3) & 7)) << 3);
  const _Float16* asrc = X  + (size_t)(m0 + s_row0) * IN_F + s_col;
  const _Float16* bsrc = Wd + (size_t)(n0 + s_row0) * IN_F + s_col;
  const int s_dst = wave * 1024;                   // wave-uniform; HW adds lane*16

  f32x4 acc[8][4] = {};
  // Fragment register classes (per modulo schedule). blo_k0 double-gen.
  f16x8 al0[4], al1[4], ah0[4], ah1[4];
  f16x8 bl0[2][2], bl1[2], bh0[2], bh1[2];

#define GLD(gsrc, ldst) __builtin_amdgcn_global_load_lds(                     \
    (const __attribute__((address_space(1))) void*)(gsrc),                    \
    (__attribute__((address_space(3))) void*)(ldst), 16, 0, 0)
#define STAGE_A(kt, bufc, i) GLD(asrc + (size_t)(kt) * BK + (size_t)(i) * 64 * IN_F, \
    smem + (bufc) * 65536 + (i) * 8192 + s_dst)
#define STAGE_B(kt, bufc, i) GLD(bsrc + (size_t)(kt) * BK + (size_t)(i) * 64 * IN_F, \
    smem + (bufc) * 65536 + 32768 + (i) * 8192 + s_dst)

#define RD_A(bufp, mm, cc) (*(const f16x8*)((bufp) + ((wm * 128 + (mm) * 16 + r16) << 7) + (cc)))
#define RD_B(bufp, nn, cc) (*(const f16x8*)((bufp) + 32768 + ((wn * 64 + (nn) * 16 + r16) << 7) + (cc)))

#define BAR   __builtin_amdgcn_s_barrier()
#define PRIO1 __builtin_amdgcn_s_setprio(1)
#define PRIO0 __builtin_amdgcn_s_setprio(0)
#define VM4 asm volatile("s_waitcnt vmcnt(4)" ::: "memory")
#define VM2 asm volatile("s_waitcnt vmcnt(2)" ::: "memory")
#define VM0 asm volatile("s_waitcnt vmcnt(0)" ::: "memory")

// T19 sched_group_barrier helpers (masks: MFMA=0x8, DS_READ=0x100,
// VMEM|VMEM_READ=0x30 for global_load_lds)
#define SGM(n) __builtin_amdgcn_sched_group_barrier(0x8, n, 0)
#define SGD(n) __builtin_amdgcn_sched_group_barrier(0x100, n, 0)
#define SGV(n) __builtin_amdgcn_sched_group_barrier(0x30, n, 0)
#define MD1 SGM(1); SGD(1)

// 8-MFMA group: 4 m-frags x 2 n-frags into acc[MO..][NO..]
#define MG(AF, BF, MO, NO)                                                    \
    _Pragma("unroll")                                                         \
    for (int m = 0; m < 4; ++m)                                               \
      _Pragma("unroll")                                                       \
      for (int n = 0; n < 2; ++n)                                             \
        acc[(MO) + m][(NO) + n] = __builtin_amdgcn_mfma_f32_16x16x32_f16(     \
            AF[m], BF[n], acc[(MO) + m][(NO) + n], 0, 0, 0)

// One K-tile. P: parity literal. SA: stage A(t+1). SB: stage B(t+2).
// GB: q6 gate vmcnt(4). GA: q7 gate mode (2 -> vmcnt(2), 0 -> vmcnt(0), -1 none).
#define TILE(P, tt, SA, SB, GB, GA) do {                                      \
    char* bufT = smem + (P) * 65536;                                          \
    char* bufN = smem + (1 - (P)) * 65536;                                    \
    /* q1: 8 MFMA, 4 reads, [2 stages] */                                     \
    if (SA) { STAGE_A((tt) + 1, 1 - (P), 0); STAGE_A((tt) + 1, 1 - (P), 1); } \
    _Pragma("unroll")                                                         \
    for (int m = 0; m < 4; ++m) al1[m] = RD_A(bufT, m, c1);                   \
    PRIO1; MG(al0, bl0[P], 0, 0); PRIO0;                                      \
    SGM(1); if (SA) { SGV(2); }                                               \
    MD1; MD1; MD1; MD1; SGM(3);                                               \
    BAR;                                                                      \
    /* q2: 8 MFMA, 2 reads, [2 stages] */                                     \
    if (SA) { STAGE_A((tt) + 1, 1 - (P), 2); STAGE_A((tt) + 1, 1 - (P), 3); } \
    _Pragma("unroll")                                                         \
    for (int n = 0; n < 2; ++n) bh1[n] = RD_B(bufT, 2 + n, c1);               \
    PRIO1; MG(al1, bl1, 0, 0); PRIO0;                                         \
    SGM(1); if (SA) { SGV(2); }                                               \
    MD1; MD1; SGM(5);                                                         \
    BAR;                                                                      \
    /* q3: 8 MFMA, 2 reads */                                                 \
    _Pragma("unroll")                                                         \
    for (int n = 0; n < 2; ++n) bh0[n] = RD_B(bufT, 2 + n, c0);               \
    PRIO1; MG(al1, bh1, 0, 2); PRIO0;                                         \
    MD1; MD1; SGM(6);                                                         \
    BAR;                                                                      \
    /* q4: 8 MFMA, 4 reads */                                                 \
    _Pragma("unroll")                                                         \
    for (int m = 0; m < 4; ++m) ah0[m] = RD_A(bufT, 4 + m, c0);               \
    PRIO1; MG(al0, bh0, 0, 2); PRIO0;                                         \
    MD1; MD1; MD1; MD1; SGM(4);                                               \
    BAR;                                                                      \
    /* q5: 8 MFMA, 4 reads */                                                 \
    _Pragma("unroll")                                                         \
    for (int m = 0; m < 4; ++m) ah1[m] = RD_A(bufT, 4 + m, c1);               \
    PRIO1; MG(ah0, bh0, 4, 2); PRIO0;                                         \
    MD1; MD1; MD1; MD1; SGM(4);                                               \
    BAR;                                                                      \
    /* q6: 8 MFMA; gate vmcnt(4) */                                           \
    PRIO1; MG(ah1, bh1, 4, 2); PRIO0;                                         \
    SGM(8);                                                                   \
    if (GB) { VM4; }                                                          \
    BAR;                                                                      \
    /* q7: 8 MFMA, 2 reads, [2 stages]; gate */                               \
    if (SB) { STAGE_B((tt) + 2, P, 0); STAGE_B((tt) + 2, P, 1); }             \
    _Pragma("unroll")                                                         \
    for (int n = 0; n < 2; ++n) bl0[1 - (P)][n] = RD_B(bufN, n, c0);          \
    PRIO1; MG(ah1, bl1, 4, 0); PRIO0;                                         \
    SGM(1); if (SB) { SGV(2); }                                               \
    MD1; MD1; SGM(5);                                                         \
    if ((GA) == 2) { VM2; }                                                   \
    if ((GA) == 0) { VM0; }                                                   \
    BAR;                                                                      \
    /* q8: 8 MFMA, 6 reads, [2 stages] */                                     \
    if (SB) { STAGE_B((tt) + 2, P, 2); STAGE_B((tt) + 2, P, 3); }             \
    _Pragma("unroll")                                                         \
    for (int m = 0; m < 4; ++m) al0[m] = RD_A(bufN, m, c0);                   \
    _Pragma("unroll")                                                         \
    for (int n = 0; n < 2; ++n) bl1[n] = RD_B(bufN, n, c1);                   \
    PRIO1; MG(ah0, bl0[P], 4, 0); PRIO0;                                      \
    SGM(1); if (SB) { SGV(2); }                                               \
    MD1; MD1; MD1; MD1; MD1; MD1; SGM(1);                                     \
    BAR;                                                                      \
  } while (0)

  // ---- Prologue: tile0 full (8 calls) + tile1 B (4 calls); enter steady state
  {
    _Pragma("unroll")
    for (int i = 0; i < 4; ++i) { STAGE_A(0, 0, i); }
    _Pragma("unroll")
    for (int i = 0; i < 4; ++i) { STAGE_B(0, 0, i); }
    _Pragma("unroll")
    for (int i = 0; i < 4; ++i) { STAGE_B(1, 1, i); }
    VM4;                                   // tile0's 8 landed; tile1-B 4 in flight
    BAR;
    // Preload registers the steady loop expects (normally read at q7/q8(t-1)):
    char* buf0p = smem;
    _Pragma("unroll")
    for (int n = 0; n < 2; ++n) bl0[0][n] = RD_B(buf0p, n, c0);
    _Pragma("unroll")
    for (int n = 0; n < 2; ++n) bl1[n] = RD_B(buf0p, n, c1);
    _Pragma("unroll")
    for (int m = 0; m < 4; ++m) al0[m] = RD_A(buf0p, m, c0);
  }

  // ---- Main loop: tiles 0..61 (full pipeline)
  #pragma unroll 1
  for (int t = 0; t < 62; t += 2) {
    TILE(0, t,     1, 1, 1, 2);
    TILE(1, t + 1, 1, 1, 1, 2);
  }
  // ---- Tail: tile 62 (stage A(63) only; drain gate), tile 63 (no stages/gates;
  // its q7/q8 prefetch-reads fetch stale LDS, dead values — harmless)
  TILE(0, 62, 1, 0, 1, 0);
  TILE(1, 63, 0, 0, 0, -1);

  // Epilogue: acc * scales[col] + bias[col], fp32, NONTEMPORAL (bypass L3:
  // OUT is write-once never-read; keeps X+W resident in L3 for staging).
  // C/D frag: col = lane&15, row = (lane>>4)*4 + reg (m89-verified).
  const int crow = (lane >> 4) << 2;
  #pragma unroll
  for (int nf = 0; nf < 4; ++nf) {
    const int col = n0 + wn * 64 + nf * 16 + r16;
    const float s = scales[col];
    const float bb = bias[col];
    #pragma unroll
    for (int mf = 0; mf < 8; ++mf) {
      const int rb = m0 + wm * 128 + mf * 16 + crow;
      #pragma unroll
      for (int r = 0; r < 4; ++r)
        __builtin_nontemporal_store(acc[mf][nf][r] * s + bb,
                                    out + (size_t)(rb + r) * OUT_F + col);
    }
  }
#undef TILE
#undef MG
#undef RD_A
#undef RD_B
#undef STAGE_A
#undef STAGE_B
#undef GLD
}

// ---------------------------------------------------------------------------
// Fallback (only if ws too small): correct but slow fp32 path.
// ---------------------------------------------------------------------------
__global__ __launch_bounds__(256) void naive_kernel(
    const float* __restrict__ x, const int* __restrict__ codes,
    const float* __restrict__ cbs, const float* __restrict__ scales,
    const float* __restrict__ bias, float* __restrict__ out)
{
  __shared__ float xrow[IN_F];
  const int m = blockIdx.x;
  for (int i = threadIdx.x; i < IN_F; i += 256)
    xrow[i] = x[(size_t)m * IN_F + i];
  __syncthreads();
  for (int o = threadIdx.x; o < OUT_F; o += 256) {
    float acc = 0.f;
    const int2* crow = (const int2*)codes + (size_t)o * NIG;
    for (int g = 0; g < NIG; ++g) {
      const int2 c = crow[g];
      const float* e0 = cbs + (size_t)c.x * 8;
      const float* e1 = cbs + (size_t)CBSZ * 8 + (size_t)c.y * 8;
      const float* xr = xrow + g * 8;
      #pragma unroll
      for (int j = 0; j < 8; ++j) acc += (e0[j] + e1[j]) * xr[j];
    }
    out[(size_t)m * OUT_F + o] = acc * scales[o] + bias[o];
  }
}

// ---------------------------------------------------------------------------
extern "C" void kernel_launch(void* const* d_in, const int* in_sizes, int n_in,
                              void* d_out, int out_size, void* d_ws, size_t ws_size,
                              hipStream_t stream) {
  const float* x      = (const float*)d_in[0];
  const int*   codes  = (const int*)d_in[1];
  const float* cbs    = (const float*)d_in[2];
  const float* scales = (const float*)d_in[3];
  const float* bias   = (const float*)d_in[4];
  float* out = (float*)d_out;

  const size_t W_BYTES = (size_t)OUT_F * IN_F * sizeof(_Float16);  // 90.2 MB
  const size_t X_BYTES = (size_t)M_ROWS * IN_F * sizeof(_Float16); // 67.1 MB

  if (ws_size < W_BYTES + X_BYTES) {
    naive_kernel<<<M_ROWS, 256, 0, stream>>>(x, codes, cbs, scales, bias, out);
    return;
  }

  _Float16* W = (_Float16*)d_ws;
  _Float16* X = (_Float16*)((char*)d_ws + W_BYTES);

  prep_kernel<<<DQ_BLOCKS + CV_BLOCKS, 256, 0, stream>>>(codes, cbs, x, W, X);
  gemm_pipe<<<GRID_MT * GRID_NT, 512, 0, stream>>>(X, W, scales, bias, out);
}